// Round 1
// 144.531 us; speedup vs baseline: 1.0297x; 1.0297x over previous
//
#include <hip/hip_runtime.h>

#define NN 4
#define CIN 256
#define CH 128       // gconv out channels = AC = oconv channels
#define HH 64
#define hh 32
#define L 1024
#define NB 2048      // CH*16
#define PENALTY -10000.0f
#define EPS 1e-4f

typedef __bf16 bf16x8 __attribute__((ext_vector_type(8)));
typedef float f32x4 __attribute__((ext_vector_type(4)));
typedef __attribute__((address_space(3))) void lds_t;
typedef __attribute__((address_space(1))) const void gbl_t;

__device__ __forceinline__ int refl32(int t) { return t < 0 ? -t : (t > 31 ? 62 - t : t); }
__device__ __forceinline__ int refl64(int t) { return t < 0 ? -t : (t > 63 ? 126 - t : t); }
// XOR-swizzle of element index (16B/8-elem granule) within a 32-elem K-chunk, keyed by row
__device__ __forceinline__ int swz(int k, int row) { return k ^ (((row >> 1) & 3) << 3); }

// ---- fused prep: img downsample+transpose (blocks 0..127), unknown stats
// ---- (blocks 128..131), weight convert (blocks 132..167) ----
__global__ void k_prep(const float* __restrict__ img, const float* __restrict__ gw,
                       const float* __restrict__ ow, const float* __restrict__ unknown,
                       __bf16* __restrict__ Xb, __bf16* __restrict__ gwb,
                       __bf16* __restrict__ owb, float* __restrict__ unk,
                       float* __restrict__ scales) {
    __shared__ float sm[CIN * 33];
    int bid = blockIdx.x, t = threadIdx.x;
    if (bid < 128) {
        // prep_x: downsample img, transpose to [np][c], pre-swizzled bf16
        int i = bid & 31, n = bid >> 5;
        for (int e = t; e < CIN * 32; e += 256) {
            int c = e >> 5, jj = e & 31;
            sm[c * 33 + jj] = img[(((size_t)n * CIN + c) * HH + 2 * i) * HH + 2 * jj];
        }
        __syncthreads();
#pragma unroll
        for (int j = 0; j < 32; ++j) {
            int np = (n << 10) + i * 32 + j;
            int cl = swz(t, np);
            Xb[(size_t)np * CIN + t] = (__bf16)sm[cl * 33 + j];
        }
    } else if (bid < 132) {
        // stats: unknown downsample, mean -> scales, 3x3 reflect box mean -> unk
        int n = bid - 128;
        float* u = sm;            // [1024]
        float* red = sm + 1024;   // [256]
        float part = 0.f;
#pragma unroll
        for (int c = 0; c < 4; ++c) {
            int idx = t + c * 256;
            int i = idx >> 5, j = idx & 31;
            float v = unknown[n * 4096 + (2 * i) * HH + 2 * j];
            u[idx] = v;
            part += v;
        }
        red[t] = part;
        __syncthreads();
        for (int s = 128; s > 0; s >>= 1) {
            if (t < s) red[t] += red[t + s];
            __syncthreads();
        }
        if (t == 0) {
            float um = red[0] / 1024.0f;
            float km = 1.0f - um;
            scales[n * 2] = fminf(fmaxf(sqrtf(um / km), 0.1f), 10.0f);
            scales[n * 2 + 1] = fminf(fmaxf(sqrtf(km / um), 0.1f), 10.0f);
        }
#pragma unroll
        for (int c = 0; c < 4; ++c) {
            int idx = t + c * 256;
            int i = idx >> 5, j = idx & 31;
            float sum = 0.f;
#pragma unroll
            for (int di = -1; di <= 1; ++di)
#pragma unroll
                for (int dj = -1; dj <= 1; ++dj)
                    sum += u[refl32(i + di) * 32 + refl32(j + dj)];
            unk[n * L + idx] = sum * (1.0f / 9.0f);
        }
    } else {
        // prep_w: weights -> bf16 pre-swizzled
        for (int e = (bid - 132) * 256 + t; e < 49152; e += 36 * 256) {
            if (e < 32768) {
                int o = e >> 8, m = e & 255;
                gwb[e] = (__bf16)gw[o * 256 + swz(m, o)];
            } else {
                int e2 = e - 32768;
                int j = e2 >> 7, m = e2 & 127;
                owb[e2] = (__bf16)ow[j * 128 + swz(m, j)];
            }
        }
    }
}

// ---- bf16 transposed alpha patches Bt[n][j][swz(q,j)], 8 q per thread ----
__global__ void k_btbuild(const float* __restrict__ alpha, __bf16* __restrict__ Bt) {
    int e = blockIdx.x * 256 + threadIdx.x;  // < 4*2048*128
    int qg = e & 127;
    int j = (e >> 7) & 2047;
    int n = e >> 18;
    int q0 = qg * 8;
    int o = j >> 4, a = (j >> 2) & 3, b = j & 3;
    int ti = refl64(2 * (q0 >> 5) + a - 1);
    const float* ap = alpha + (((size_t)n * CH + o) * HH + ti) * HH;
    int qj0 = q0 & 31;
    __bf16 v[8];
#pragma unroll
    for (int s = 0; s < 8; ++s) {
        int tj = refl64(2 * (qj0 + s) + b - 1);
        v[s] = (__bf16)ap[tj];
    }
    *(bf16x8*)(Bt + (((size_t)n * NB + j) << 10) + swz(q0, j)) = *(bf16x8*)v;
}

// ---- MFMA GEMM0: gbf[np][o] = Xb . gwb^T + gb, bf16 out ----
__global__ __launch_bounds__(256, 2) void k_gemm0(const __bf16* __restrict__ Xb,
                                                  const __bf16* __restrict__ gwb,
                                                  const float* __restrict__ gb,
                                                  __bf16* __restrict__ gbf) {
    __shared__ __align__(16) __bf16 As[128 * 32];
    __shared__ __align__(16) __bf16 Bs[128 * 32];
    int p0 = blockIdx.x * 128;
    int t = threadIdx.x, l = t & 63, w = t >> 6;
    int wr = w >> 1, wc = w & 1;
    f32x4 acc[4][4] = {};
    for (int k0 = 0; k0 < CIN; k0 += 32) {
#pragma unroll
        for (int i = 0; i < 2; ++i) {
            const __bf16* srcA = Xb + (size_t)(p0 + i * 64 + (t >> 2)) * CIN + k0 + (t & 3) * 8;
            __builtin_amdgcn_global_load_lds((gbl_t*)srcA, (lds_t*)(As + i * 2048 + t * 8), 16, 0, 0);
            const __bf16* srcB = gwb + (size_t)(i * 64 + (t >> 2)) * CIN + k0 + (t & 3) * 8;
            __builtin_amdgcn_global_load_lds((gbl_t*)srcB, (lds_t*)(Bs + i * 2048 + t * 8), 16, 0, 0);
        }
        __syncthreads();
        int gl = l >> 4, r = l & 15;
        bf16x8 av[4], bv[4];
#pragma unroll
        for (int m = 0; m < 4; ++m) {
            int row = wr * 64 + m * 16 + r;
            av[m] = *(const bf16x8*)(As + row * 32 + swz(gl << 3, row));
            int col = wc * 64 + m * 16 + r;
            bv[m] = *(const bf16x8*)(Bs + col * 32 + swz(gl << 3, col));
        }
#pragma unroll
        for (int m = 0; m < 4; ++m)
#pragma unroll
            for (int c2 = 0; c2 < 4; ++c2)
                acc[m][c2] = __builtin_amdgcn_mfma_f32_16x16x32_bf16(av[m], bv[c2], acc[m][c2], 0, 0, 0);
        __syncthreads();
    }
    int r = l & 15, hi = l >> 4;
#pragma unroll
    for (int m = 0; m < 4; ++m)
#pragma unroll
        for (int c2 = 0; c2 < 4; ++c2) {
            int o = wc * 64 + c2 * 16 + r;
            float bias = gb[o];
#pragma unroll
            for (int reg = 0; reg < 4; ++reg) {
                int row = p0 + wr * 64 + m * 16 + hi * 4 + reg;
                gbf[((size_t)row << 7) + o] = (__bf16)(acc[m][c2][reg] + bias);
            }
        }
}

// ---- fused ssq + normf: per-row ssq of gbf (LDS), 3x3 sum, f[q] ----
__global__ void k_ssqf(const __bf16* __restrict__ gbf, const float* __restrict__ unk,
                       const float* __restrict__ scales, float* __restrict__ f) {
    __shared__ float ssqs[1024];
    int n = blockIdx.x, t = threadIdx.x;
#pragma unroll
    for (int c = 0; c < 4; ++c) {
        int row = t + c * 256;
        const __bf16* rp = gbf + (((size_t)(n << 10) + row) << 7);
        float s = 0.f;
#pragma unroll
        for (int kk = 0; kk < 16; ++kk) {
            bf16x8 v = *(const bf16x8*)(rp + kk * 8);
#pragma unroll
            for (int u2 = 0; u2 < 8; ++u2) {
                float x = (float)v[u2];
                s += x * x;
            }
        }
        ssqs[row] = s;
    }
    __syncthreads();
    float us = scales[n * 2], ks = scales[n * 2 + 1];
#pragma unroll
    for (int c = 0; c < 4; ++c) {
        int p = t + c * 256;
        int pi = p >> 5, pj = p & 31;
        float sum = 0.f;
#pragma unroll
        for (int di = -1; di <= 1; ++di)
#pragma unroll
            for (int dj = -1; dj <= 1; ++dj)
                sum += ssqs[refl32(pi + di) * 32 + refl32(pj + dj)];
        float norm = sqrtf(sum);
        float sc = unk[n * L + p] > 0.f ? us : ks;
        f[n * L + p] = sc / fmaxf(norm, EPS);
    }
}

// ---- MFMA GEMM1: whole 6x32-row gbf window (3x3 taps + reflect halo) staged
// ---- to LDS once; 576 MFMAs barrier-free. LDS chunk-major [4][192][32]. ----
__global__ __launch_bounds__(256, 1) void k_gemm1(const __bf16* __restrict__ gbf,
                                                  const float* __restrict__ f,
                                                  const float* __restrict__ unk,
                                                  float* __restrict__ W) {
    __shared__ __align__(16) __bf16 As[4 * 6144];  // [chunk][192 rows][32]
    __shared__ __align__(16) __bf16 Bs[4 * 6144];
    int n = blockIdx.z;
    int p0 = blockIdx.y * 128, q0 = blockIdx.x * 128;
    const __bf16* gn = gbf + ((size_t)n << 17);
    int t = threadIdx.x, l = t & 63, w = t >> 6;
    int wr = w >> 1, wc = w & 1;
    int by4 = blockIdx.y * 4, bx4 = blockIdx.x * 4;
    int rbA = by4 - 1; rbA = rbA < 0 ? 0 : (rbA > 26 ? 26 : rbA);
    int rbB = bx4 - 1; rbB = rbB < 0 ? 0 : (rbB > 26 ? 26 : rbB);
    // stage 6 grid-rows x 32 cols x 128 ch per panel (48 KB each), source pre-swizzled
    // per LDS row; dest linear per chunk -> [chunk][wrow][sg] with sg = src_g ^ key(wrow)
#pragma unroll
    for (int k = 0; k < 12; ++k) {
        int chunk = k / 3;
        int rem = (k % 3) * 256 + t;           // granule within chunk-plane [0,768)
        int wrow = rem >> 2, sg = rem & 3;
        int so = (chunk << 5) + ((sg ^ ((wrow >> 1) & 3)) << 3);
        int grA = ((rbA + (wrow >> 5)) << 5) + (wrow & 31);
        __builtin_amdgcn_global_load_lds((gbl_t*)(gn + (size_t)grA * 128 + so),
                                         (lds_t*)(As + chunk * 6144 + rem * 8), 16, 0, 0);
        int grB = ((rbB + (wrow >> 5)) << 5) + (wrow & 31);
        __builtin_amdgcn_global_load_lds((gbl_t*)(gn + (size_t)grB * 128 + so),
                                         (lds_t*)(Bs + chunk * 6144 + rem * 8), 16, 0, 0);
    }
    __syncthreads();
    int gl = l >> 4, r = l & 15;
    // tap address split: row-part (dk) and col-part (dl); XOR key depends only on col-part
    int rpA[4][3], cpA[4][3], rpB[4][3], cpB[4][3];
#pragma unroll
    for (int m = 0; m < 4; ++m) {
        int prow = wr * 64 + m * 16 + r;
        int qrow = wc * 64 + m * 16 + r;
#pragma unroll
        for (int d = 0; d < 3; ++d) {
            rpA[m][d] = (refl32(by4 + (prow >> 5) + d - 1) - rbA) << 10;
            int cp = refl32((prow & 31) + d - 1);
            cpA[m][d] = cp * 32 + ((gl ^ ((cp >> 1) & 3)) << 3);
            rpB[m][d] = (refl32(bx4 + (qrow >> 5) + d - 1) - rbB) << 10;
            int cq = refl32((qrow & 31) + d - 1);
            cpB[m][d] = cq * 32 + ((gl ^ ((cq >> 1) & 3)) << 3);
        }
    }
    f32x4 acc[4][4] = {};
#pragma unroll
    for (int dk = 0; dk < 3; ++dk)
#pragma unroll
        for (int dl = 0; dl < 3; ++dl)
#pragma unroll
            for (int cc = 0; cc < 4; ++cc) {
                bf16x8 av[4], bv[4];
#pragma unroll
                for (int m = 0; m < 4; ++m) {
                    av[m] = *(const bf16x8*)(As + cc * 6144 + rpA[m][dk] + cpA[m][dl]);
                    bv[m] = *(const bf16x8*)(Bs + cc * 6144 + rpB[m][dk] + cpB[m][dl]);
                }
#pragma unroll
                for (int m = 0; m < 4; ++m)
#pragma unroll
                    for (int c2 = 0; c2 < 4; ++c2)
                        acc[m][c2] = __builtin_amdgcn_mfma_f32_16x16x32_bf16(av[m], bv[c2], acc[m][c2], 0, 0, 0);
            }
    int hi = l >> 4;
#pragma unroll
    for (int m = 0; m < 4; ++m)
#pragma unroll
        for (int c2 = 0; c2 < 4; ++c2) {
            int q = q0 + wc * 64 + c2 * 16 + r;
            float fq = f[n * L + q];
#pragma unroll
            for (int reg = 0; reg < 4; ++reg) {
                int p = p0 + wr * 64 + m * 16 + hi * 4 + reg;
                float val = acc[m][c2][reg] * fq;
                if (p == q) val += PENALTY * unk[n * L + p];
                W[((size_t)n << 20) + ((size_t)p << 10) + q] = val;
            }
        }
}

// ---- row softmax over q; writes swizzled bf16 Wb ----
__global__ void k_softmax(const float* __restrict__ W, __bf16* __restrict__ Wb) {
    __shared__ float red[256];
    int row = blockIdx.x;  // n*L + p
    int p = row & (L - 1);
    const float* Wr = W + (size_t)row * 1024;
    __bf16* Wbr = Wb + (size_t)row * 1024;
    int t = threadIdx.x;
    float v[4];
    float mx = -1e30f;
#pragma unroll
    for (int ll = 0; ll < 4; ++ll) {
        v[ll] = Wr[t + ll * 256];
        mx = fmaxf(mx, v[ll]);
    }
    red[t] = mx;
    __syncthreads();
    for (int s = 128; s > 0; s >>= 1) {
        if (t < s) red[t] = fmaxf(red[t], red[t + s]);
        __syncthreads();
    }
    mx = red[0];
    __syncthreads();
    float sum = 0.f;
#pragma unroll
    for (int ll = 0; ll < 4; ++ll) {
        v[ll] = __expf(v[ll] - mx);
        sum += v[ll];
    }
    red[t] = sum;
    __syncthreads();
    for (int s = 128; s > 0; s >>= 1) {
        if (t < s) red[t] += red[t + s];
        __syncthreads();
    }
    float inv = 1.0f / red[0];
#pragma unroll
    for (int ll = 0; ll < 4; ++ll) Wbr[swz(t + ll * 256, p)] = (__bf16)(v[ll] * inv);
}

// ---- MFMA GEMM2: Tb[p][j] = sum_q W[p][q] * Bt[j][q], 2-phase dbuf BK=64 ----
__global__ __launch_bounds__(256, 2) void k_gemm2(const __bf16* __restrict__ Wb,
                                                  const __bf16* __restrict__ Bt,
                                                  __bf16* __restrict__ Tb) {
    // bijective XCD-chunked remap: each XCD owns (n, p-half) -> L2-resident A panels
    int bid = blockIdx.x;
    int xcd = bid & 7, idx = bid >> 3;
    int n = xcd >> 1;
    int p0 = ((xcd & 1) * 4 + (idx & 3)) * 128;
    int j0 = (idx >> 2) * 128;
    __shared__ __align__(16) __bf16 As[2][2][4096];  // [buf][ks][128 rows][32]
    __shared__ __align__(16) __bf16 Bs[2][2][4096];
    const __bf16* An = Wb + ((size_t)n << 20);
    const __bf16* Bn = Bt + ((size_t)n * NB << 10);
    int t = threadIdx.x, l = t & 63, w = t >> 6;
    int wr = w >> 1, wc = w & 1;
    int gl = l >> 4, r = l & 15;
    f32x4 acc[4][4] = {};

    auto stage = [&](int buf, int k0) {
#pragma unroll
        for (int jj = 0; jj < 4; ++jj) {
            int ks = jj >> 1;
            int rem = (jj & 1) * 256 + t;  // granule within [ks] plane, [0,512)
            int row = rem >> 2, sg = rem & 3;
            const __bf16* srcA = An + ((size_t)(p0 + row) << 10) + k0 + ks * 32 + sg * 8;
            __builtin_amdgcn_global_load_lds((gbl_t*)srcA, (lds_t*)(&As[buf][ks][rem * 8]), 16, 0, 0);
            const __bf16* srcB = Bn + ((size_t)(j0 + row) << 10) + k0 + ks * 32 + sg * 8;
            __builtin_amdgcn_global_load_lds((gbl_t*)srcB, (lds_t*)(&Bs[buf][ks][rem * 8]), 16, 0, 0);
        }
    };
    auto compute = [&](int buf) {
#pragma unroll
        for (int ks = 0; ks < 2; ++ks) {
            bf16x8 av[4], bv[4];
#pragma unroll
            for (int m = 0; m < 4; ++m) {
                int row = wr * 64 + m * 16 + r;
                av[m] = *(const bf16x8*)(&As[buf][ks][row * 32 + ((gl ^ ((row >> 1) & 3)) << 3)]);
                int col = wc * 64 + m * 16 + r;
                bv[m] = *(const bf16x8*)(&Bs[buf][ks][col * 32 + ((gl ^ ((col >> 1) & 3)) << 3)]);
            }
#pragma unroll
            for (int m = 0; m < 4; ++m)
#pragma unroll
                for (int c2 = 0; c2 < 4; ++c2)
                    acc[m][c2] = __builtin_amdgcn_mfma_f32_16x16x32_bf16(av[m], bv[c2], acc[m][c2], 0, 0, 0);
        }
    };

    stage(0, 0);
    __syncthreads();
    int cur = 0;
    for (int it = 0; it < 15; ++it) {
        stage(cur ^ 1, (it + 1) * 64);  // loads fly while we compute cur
        compute(cur);
        __syncthreads();                // drains vmcnt -> next buf ready
        cur ^= 1;
    }
    compute(cur);
    int hi = l >> 4;
#pragma unroll
    for (int m = 0; m < 4; ++m)
#pragma unroll
        for (int c2 = 0; c2 < 4; ++c2) {
            int j = j0 + wc * 64 + c2 * 16 + r;
#pragma unroll
            for (int reg = 0; reg < 4; ++reg) {
                int p = p0 + wr * 64 + m * 16 + hi * 4 + reg;
                Tb[((size_t)n * L + p) * NB + j] = (__bf16)acc[m][c2][reg];
            }
        }
}

// ---- gather of Tb taps -> prop[n][pix][swz(o,pix)] bf16, /4 ----
__global__ void k_gather(const __bf16* __restrict__ Tb, __bf16* __restrict__ prop) {
    int e = blockIdx.x * 256 + threadIdx.x;  // < 2097152
    int op = e & 127;
    int pix = (e >> 7) & 4095;
    int n = e >> 19;
    int x = pix & 63, y = pix >> 6;
    int o = swz(op, pix);
    float acc = 0.f;
    int ap = (y + 1) & 1, bp = (x + 1) & 1;
#pragma unroll
    for (int da = 0; da < 2; ++da) {
        int a = ap + 2 * da;
        int ny = y + 1 - a;
        if (ny < 0 || ny >= 64) continue;
        int py = ny >> 1;
#pragma unroll
        for (int db = 0; db < 2; ++db) {
            int b = bp + 2 * db;
            int nx = x + 1 - b;
            if (nx < 0 || nx >= 64) continue;
            int px = nx >> 1;
            acc += (float)Tb[(((size_t)n * L + py * hh + px) << 11) + o * 16 + a * 4 + b];
        }
    }
    prop[e] = (__bf16)(acc * 0.25f);
}

// ---- MFMA oconv: y2[n][j][pix] = sum_o ow[j][o] * prop[n][pix][o], f32 NCHW out ----
__global__ __launch_bounds__(256, 2) void k_oconv(const __bf16* __restrict__ owb,
                                                  const __bf16* __restrict__ prop,
                                                  float* __restrict__ y2) {
    __shared__ __align__(16) __bf16 As[128 * 32];
    __shared__ __align__(16) __bf16 Bs[128 * 32];
    int n = blockIdx.z;
    int x0 = blockIdx.x * 128;
    const __bf16* Bn = prop + ((size_t)n << 19);
    int t = threadIdx.x, l = t & 63, w = t >> 6;
    int wr = w >> 1, wc = w & 1;
    f32x4 acc[4][4] = {};
    for (int k0 = 0; k0 < CH; k0 += 32) {
#pragma unroll
        for (int i = 0; i < 2; ++i) {
            const __bf16* srcA = owb + (size_t)(i * 64 + (t >> 2)) * CH + k0 + (t & 3) * 8;
            __builtin_amdgcn_global_load_lds((gbl_t*)srcA, (lds_t*)(As + i * 2048 + t * 8), 16, 0, 0);
            const __bf16* srcB = Bn + (size_t)(x0 + i * 64 + (t >> 2)) * CH + k0 + (t & 3) * 8;
            __builtin_amdgcn_global_load_lds((gbl_t*)srcB, (lds_t*)(Bs + i * 2048 + t * 8), 16, 0, 0);
        }
        __syncthreads();
        int gl = l >> 4, r = l & 15;
        bf16x8 av[4], bv[4];
#pragma unroll
        for (int m = 0; m < 4; ++m) {
            int row = wr * 64 + m * 16 + r;
            av[m] = *(const bf16x8*)(As + row * 32 + swz(gl << 3, row));
            int col = x0 + wc * 64 + m * 16 + r;
            bv[m] = *(const bf16x8*)(Bs + (wc * 64 + m * 16 + r) * 32 + swz(gl << 3, col));
        }
#pragma unroll
        for (int m = 0; m < 4; ++m)
#pragma unroll
            for (int c2 = 0; c2 < 4; ++c2)
                acc[m][c2] = __builtin_amdgcn_mfma_f32_16x16x32_bf16(av[m], bv[c2], acc[m][c2], 0, 0, 0);
        __syncthreads();
    }
    int r = l & 15, hi = l >> 4;
#pragma unroll
    for (int m = 0; m < 4; ++m)
#pragma unroll
        for (int c2 = 0; c2 < 4; ++c2) {
            int pix = x0 + wc * 64 + c2 * 16 + r;
#pragma unroll
            for (int reg = 0; reg < 4; ++reg) {
                int j = wr * 64 + m * 16 + hi * 4 + reg;
                y2[(((size_t)n * CH + j) << 12) + pix] = acc[m][c2][reg];
            }
        }
}

// ---- per-channel BN stats (deterministic two-stage) ----
__global__ void k_bnstats(const float* __restrict__ y2, float* __restrict__ stats) {
    __shared__ float r1[256], r2[256];
    int oc = blockIdx.x, t = threadIdx.x;
    float s = 0.f, s2 = 0.f;
    for (int n = 0; n < NN; ++n) {
        const float* base = y2 + (((size_t)n * CH + oc) << 12);
        for (int pix = t; pix < 4096; pix += 256) {
            float v = base[pix];
            s += v;
            s2 += v * v;
        }
    }
    r1[t] = s;
    r2[t] = s2;
    __syncthreads();
    for (int st = 128; st > 0; st >>= 1) {
        if (t < st) {
            r1[t] += r1[t + st];
            r2[t] += r2[t + st];
        }
        __syncthreads();
    }
    if (t == 0) {
        stats[oc * 2] = r1[0];
        stats[oc * 2 + 1] = r2[0];
    }
}

// ---- BN normalize + residual ----
__global__ void k_final(const float* __restrict__ y2, const float* __restrict__ stats,
                        const float* __restrict__ gamma, const float* __restrict__ beta,
                        const float* __restrict__ alpha, float* __restrict__ out) {
    int e = blockIdx.x * 256 + threadIdx.x;
    int oc = (e >> 12) & 127;
    float s1 = stats[oc * 2], s2 = stats[oc * 2 + 1];
    float mu = s1 * (1.0f / 16384.0f);
    float var = s2 * (1.0f / 16384.0f) - mu * mu;
    float inv = rsqrtf(var + 1e-5f);
    out[e] = (y2[e] - mu) * inv * gamma[oc] + beta[oc] + alpha[e];
}

extern "C" void kernel_launch(void* const* d_in, const int* in_sizes, int n_in,
                              void* d_out, int out_size, void* d_ws, size_t ws_size,
                              hipStream_t stream) {
    const float* img = (const float*)d_in[0];
    const float* alpha = (const float*)d_in[1];
    const float* unknown = (const float*)d_in[2];
    const float* gw = (const float*)d_in[3];
    const float* gb = (const float*)d_in[4];
    const float* ow = (const float*)d_in[5];
    const float* gamma = (const float*)d_in[6];
    const float* beta = (const float*)d_in[7];
    float* out = (float*)d_out;
    float* ws = (float*)d_ws;

    // layout (float-word offsets)
    __bf16* Xb = (__bf16*)(ws);                // 524288 fw
    __bf16* gwb = (__bf16*)(ws + 524288);      // 16384 fw
    __bf16* owb = (__bf16*)(ws + 540672);      // 8192 fw
    __bf16* gbf = (__bf16*)(ws + 548864);      // 262144 fw  (4096x128 bf16)
    float* f = ws + 811008;                    // 4096
    float* unk = ws + 815104;                  // 4096
    float* scales = ws + 819200;               // 64
    float* stats = ws + 819264;                // 256
    float* W = ws + 819520;                    // 4194304 fw
    __bf16* Wb = (__bf16*)(ws + 5013824);      // 2097152 fw
    __bf16* Bt = (__bf16*)(ws + 7110976);      // 4194304 fw
    __bf16* Tb = (__bf16*)(ws + 11305280);     // 4194304 fw
    __bf16* prop = (__bf16*)(ws + 15499584);   // 1048576 fw
    float* y2 = ws + 16548160;                 // 2097152 fw
    // total 18,645,312 fw ≈ 74.6 MB

    k_prep<<<168, 256, 0, stream>>>(img, gw, ow, unknown, Xb, gwb, owb, unk, scales);
    k_btbuild<<<4096, 256, 0, stream>>>(alpha, Bt);
    k_gemm0<<<32, 256, 0, stream>>>(Xb, gwb, gb, gbf);
    k_ssqf<<<4, 256, 0, stream>>>(gbf, unk, scales, f);
    k_gemm1<<<dim3(8, 8, 4), 256, 0, stream>>>(gbf, f, unk, W);
    k_softmax<<<4096, 256, 0, stream>>>(W, Wb);
    k_gemm2<<<512, 256, 0, stream>>>(Wb, Bt, Tb);
    k_gather<<<8192, 256, 0, stream>>>(Tb, prop);
    k_oconv<<<dim3(32, 1, 4), 256, 0, stream>>>(owb, prop, y2);
    k_bnstats<<<128, 256, 0, stream>>>(y2, stats);
    k_final<<<8192, 256, 0, stream>>>(y2, stats, gamma, beta, alpha, out);
}

// Round 2
// 113.785 us; speedup vs baseline: 1.3079x; 1.2702x over previous
//
#include <hip/hip_runtime.h>

#define NN 4
#define CIN 256
#define CH 128       // gconv out channels = AC = oconv channels
#define HH 64
#define hh 32
#define L 1024
#define NB 2048      // CH*16
#define PENALTY -10000.0f
#define EPS 1e-4f

typedef __bf16 bf16x8 __attribute__((ext_vector_type(8)));
typedef float f32x4 __attribute__((ext_vector_type(4)));
typedef __attribute__((address_space(3))) void lds_t;
typedef __attribute__((address_space(1))) const void gbl_t;

__device__ __forceinline__ int refl32(int t) { return t < 0 ? -t : (t > 31 ? 62 - t : t); }
__device__ __forceinline__ int refl64(int t) { return t < 0 ? -t : (t > 63 ? 126 - t : t); }
// XOR-swizzle of element index (16B/8-elem granule) within a 32-elem K-chunk, keyed by row
__device__ __forceinline__ int swz(int k, int row) { return k ^ (((row >> 1) & 3) << 3); }

// ---- fused prep: img downsample+transpose (blocks 0..127), unknown stats
// ---- (blocks 128..131), weight convert (blocks 132..167) ----
__global__ void k_prep(const float* __restrict__ img, const float* __restrict__ gw,
                       const float* __restrict__ ow, const float* __restrict__ unknown,
                       __bf16* __restrict__ Xb, __bf16* __restrict__ gwb,
                       __bf16* __restrict__ owb, float* __restrict__ unk,
                       float* __restrict__ scales) {
    __shared__ float sm[CIN * 33];
    int bid = blockIdx.x, t = threadIdx.x;
    if (bid < 128) {
        // prep_x: downsample img, transpose to [np][c], pre-swizzled bf16
        int i = bid & 31, n = bid >> 5;
        for (int e = t; e < CIN * 32; e += 256) {
            int c = e >> 5, jj = e & 31;
            sm[c * 33 + jj] = img[(((size_t)n * CIN + c) * HH + 2 * i) * HH + 2 * jj];
        }
        __syncthreads();
#pragma unroll
        for (int j = 0; j < 32; ++j) {
            int np = (n << 10) + i * 32 + j;
            int cl = swz(t, np);
            Xb[(size_t)np * CIN + t] = (__bf16)sm[cl * 33 + j];
        }
    } else if (bid < 132) {
        // stats: unknown downsample, mean -> scales, 3x3 reflect box mean -> unk
        int n = bid - 128;
        float* u = sm;            // [1024]
        float* red = sm + 1024;   // [256]
        float part = 0.f;
#pragma unroll
        for (int c = 0; c < 4; ++c) {
            int idx = t + c * 256;
            int i = idx >> 5, j = idx & 31;
            float v = unknown[n * 4096 + (2 * i) * HH + 2 * j];
            u[idx] = v;
            part += v;
        }
        red[t] = part;
        __syncthreads();
        for (int s = 128; s > 0; s >>= 1) {
            if (t < s) red[t] += red[t + s];
            __syncthreads();
        }
        if (t == 0) {
            float um = red[0] / 1024.0f;
            float km = 1.0f - um;
            scales[n * 2] = fminf(fmaxf(sqrtf(um / km), 0.1f), 10.0f);
            scales[n * 2 + 1] = fminf(fmaxf(sqrtf(km / um), 0.1f), 10.0f);
        }
#pragma unroll
        for (int c = 0; c < 4; ++c) {
            int idx = t + c * 256;
            int i = idx >> 5, j = idx & 31;
            float sum = 0.f;
#pragma unroll
            for (int di = -1; di <= 1; ++di)
#pragma unroll
                for (int dj = -1; dj <= 1; ++dj)
                    sum += u[refl32(i + di) * 32 + refl32(j + dj)];
            unk[n * L + idx] = sum * (1.0f / 9.0f);
        }
    } else {
        // prep_w: weights -> bf16 pre-swizzled
        for (int e = (bid - 132) * 256 + t; e < 49152; e += 36 * 256) {
            if (e < 32768) {
                int o = e >> 8, m = e & 255;
                gwb[e] = (__bf16)gw[o * 256 + swz(m, o)];
            } else {
                int e2 = e - 32768;
                int j = e2 >> 7, m = e2 & 127;
                owb[e2] = (__bf16)ow[j * 128 + swz(m, j)];
            }
        }
    }
}

// ---- bf16 transposed alpha patches, j' = (a*4+b)*128 + o ordering.
// ---- One block per (n,o): stage alpha plane in LDS (coalesced), emit 16 ab rows. ----
__global__ void k_btbuild(const float* __restrict__ alpha, __bf16* __restrict__ Bt) {
    __shared__ float sm[64 * 65];
    int blk = blockIdx.x;          // 512 = n(4) * o(128)
    int n = blk >> 7, o = blk & 127;
    int t = threadIdx.x;
    const float* ap = alpha + ((size_t)(n * CH + o) << 12);
#pragma unroll
    for (int j = 0; j < 4; ++j) {
        int fi = t + j * 256;      // float4 index 0..1023
        int row = fi >> 4, c4 = fi & 15;
        float4 v = *(const float4*)(ap + fi * 4);
        float* d = sm + row * 65 + c4 * 4;
        d[0] = v.x; d[1] = v.y; d[2] = v.z; d[3] = v.w;
    }
    __syncthreads();
    __bf16* Bn = Bt + ((size_t)(n * NB) << 10);
#pragma unroll
    for (int gi = 0; gi < 8; ++gi) {
        int g = gi * 256 + t;      // granule 0..2047
        int ab = g >> 7, qg = g & 127;
        int a = ab >> 2, bb = ab & 3;
        int q0 = qg * 8;
        int qi = q0 >> 5, qj0 = q0 & 31;
        int ti = refl64(2 * qi + a - 1);
        const float* r = sm + ti * 65;
        __bf16 v[8];
#pragma unroll
        for (int s = 0; s < 8; ++s) v[s] = (__bf16)r[refl64(2 * (qj0 + s) + bb - 1)];
        int j = ab * 128 + o;
        *(bf16x8*)(Bn + ((size_t)j << 10) + swz(q0, j)) = *(bf16x8*)v;
    }
}

// ---- MFMA GEMM0: gbf[np][o] = Xb . gwb^T + gb, bf16 out ----
__global__ __launch_bounds__(256, 2) void k_gemm0(const __bf16* __restrict__ Xb,
                                                  const __bf16* __restrict__ gwb,
                                                  const float* __restrict__ gb,
                                                  __bf16* __restrict__ gbf) {
    __shared__ __align__(16) __bf16 As[128 * 32];
    __shared__ __align__(16) __bf16 Bs[128 * 32];
    int p0 = blockIdx.x * 128;
    int t = threadIdx.x, l = t & 63, w = t >> 6;
    int wr = w >> 1, wc = w & 1;
    f32x4 acc[4][4] = {};
    for (int k0 = 0; k0 < CIN; k0 += 32) {
#pragma unroll
        for (int i = 0; i < 2; ++i) {
            const __bf16* srcA = Xb + (size_t)(p0 + i * 64 + (t >> 2)) * CIN + k0 + (t & 3) * 8;
            __builtin_amdgcn_global_load_lds((gbl_t*)srcA, (lds_t*)(As + i * 2048 + t * 8), 16, 0, 0);
            const __bf16* srcB = gwb + (size_t)(i * 64 + (t >> 2)) * CIN + k0 + (t & 3) * 8;
            __builtin_amdgcn_global_load_lds((gbl_t*)srcB, (lds_t*)(Bs + i * 2048 + t * 8), 16, 0, 0);
        }
        __syncthreads();
        int gl = l >> 4, r = l & 15;
        bf16x8 av[4], bv[4];
#pragma unroll
        for (int m = 0; m < 4; ++m) {
            int row = wr * 64 + m * 16 + r;
            av[m] = *(const bf16x8*)(As + row * 32 + swz(gl << 3, row));
            int col = wc * 64 + m * 16 + r;
            bv[m] = *(const bf16x8*)(Bs + col * 32 + swz(gl << 3, col));
        }
#pragma unroll
        for (int m = 0; m < 4; ++m)
#pragma unroll
            for (int c2 = 0; c2 < 4; ++c2)
                acc[m][c2] = __builtin_amdgcn_mfma_f32_16x16x32_bf16(av[m], bv[c2], acc[m][c2], 0, 0, 0);
        __syncthreads();
    }
    int r = l & 15, hi = l >> 4;
#pragma unroll
    for (int m = 0; m < 4; ++m)
#pragma unroll
        for (int c2 = 0; c2 < 4; ++c2) {
            int o = wc * 64 + c2 * 16 + r;
            float bias = gb[o];
#pragma unroll
            for (int reg = 0; reg < 4; ++reg) {
                int row = p0 + wr * 64 + m * 16 + hi * 4 + reg;
                gbf[((size_t)row << 7) + o] = (__bf16)(acc[m][c2][reg] + bias);
            }
        }
}

// ---- fused ssq + normf: per-row ssq of gbf (LDS), 3x3 sum, f[q] ----
__global__ void k_ssqf(const __bf16* __restrict__ gbf, const float* __restrict__ unk,
                       const float* __restrict__ scales, float* __restrict__ f) {
    __shared__ float ssqs[1024];
    int n = blockIdx.x, t = threadIdx.x;
#pragma unroll
    for (int c = 0; c < 4; ++c) {
        int row = t + c * 256;
        const __bf16* rp = gbf + (((size_t)(n << 10) + row) << 7);
        float s = 0.f;
#pragma unroll
        for (int kk = 0; kk < 16; ++kk) {
            bf16x8 v = *(const bf16x8*)(rp + kk * 8);
#pragma unroll
            for (int u2 = 0; u2 < 8; ++u2) {
                float x = (float)v[u2];
                s += x * x;
            }
        }
        ssqs[row] = s;
    }
    __syncthreads();
    float us = scales[n * 2], ks = scales[n * 2 + 1];
#pragma unroll
    for (int c = 0; c < 4; ++c) {
        int p = t + c * 256;
        int pi = p >> 5, pj = p & 31;
        float sum = 0.f;
#pragma unroll
        for (int di = -1; di <= 1; ++di)
#pragma unroll
            for (int dj = -1; dj <= 1; ++dj)
                sum += ssqs[refl32(pi + di) * 32 + refl32(pj + dj)];
        float norm = sqrtf(sum);
        float sc = unk[n * L + p] > 0.f ? us : ks;
        f[n * L + p] = sc / fmaxf(norm, EPS);
    }
}

// ---- MFMA GEMM1: whole 6x32-row gbf window (3x3 taps + reflect halo) staged
// ---- to LDS once; 576 MFMAs barrier-free. LDS chunk-major [4][192][32]. ----
__global__ __launch_bounds__(256, 1) void k_gemm1(const __bf16* __restrict__ gbf,
                                                  const float* __restrict__ f,
                                                  const float* __restrict__ unk,
                                                  float* __restrict__ W) {
    __shared__ __align__(16) __bf16 As[4 * 6144];  // [chunk][192 rows][32]
    __shared__ __align__(16) __bf16 Bs[4 * 6144];
    int n = blockIdx.z;
    int p0 = blockIdx.y * 128, q0 = blockIdx.x * 128;
    const __bf16* gn = gbf + ((size_t)n << 17);
    int t = threadIdx.x, l = t & 63, w = t >> 6;
    int wr = w >> 1, wc = w & 1;
    int by4 = blockIdx.y * 4, bx4 = blockIdx.x * 4;
    int rbA = by4 - 1; rbA = rbA < 0 ? 0 : (rbA > 26 ? 26 : rbA);
    int rbB = bx4 - 1; rbB = rbB < 0 ? 0 : (rbB > 26 ? 26 : rbB);
    // stage 6 grid-rows x 32 cols x 128 ch per panel (48 KB each), source pre-swizzled
    // per LDS row; dest linear per chunk -> [chunk][wrow][sg] with sg = src_g ^ key(wrow)
#pragma unroll
    for (int k = 0; k < 12; ++k) {
        int chunk = k / 3;
        int rem = (k % 3) * 256 + t;           // granule within chunk-plane [0,768)
        int wrow = rem >> 2, sg = rem & 3;
        int so = (chunk << 5) + ((sg ^ ((wrow >> 1) & 3)) << 3);
        int grA = ((rbA + (wrow >> 5)) << 5) + (wrow & 31);
        __builtin_amdgcn_global_load_lds((gbl_t*)(gn + (size_t)grA * 128 + so),
                                         (lds_t*)(As + chunk * 6144 + rem * 8), 16, 0, 0);
        int grB = ((rbB + (wrow >> 5)) << 5) + (wrow & 31);
        __builtin_amdgcn_global_load_lds((gbl_t*)(gn + (size_t)grB * 128 + so),
                                         (lds_t*)(Bs + chunk * 6144 + rem * 8), 16, 0, 0);
    }
    __syncthreads();
    int gl = l >> 4, r = l & 15;
    // tap address split: row-part (dk) and col-part (dl); XOR key depends only on col-part
    int rpA[4][3], cpA[4][3], rpB[4][3], cpB[4][3];
#pragma unroll
    for (int m = 0; m < 4; ++m) {
        int prow = wr * 64 + m * 16 + r;
        int qrow = wc * 64 + m * 16 + r;
#pragma unroll
        for (int d = 0; d < 3; ++d) {
            rpA[m][d] = (refl32(by4 + (prow >> 5) + d - 1) - rbA) << 10;
            int cp = refl32((prow & 31) + d - 1);
            cpA[m][d] = cp * 32 + ((gl ^ ((cp >> 1) & 3)) << 3);
            rpB[m][d] = (refl32(bx4 + (qrow >> 5) + d - 1) - rbB) << 10;
            int cq = refl32((qrow & 31) + d - 1);
            cpB[m][d] = cq * 32 + ((gl ^ ((cq >> 1) & 3)) << 3);
        }
    }
    f32x4 acc[4][4] = {};
#pragma unroll
    for (int dk = 0; dk < 3; ++dk)
#pragma unroll
        for (int dl = 0; dl < 3; ++dl)
#pragma unroll
            for (int cc = 0; cc < 4; ++cc) {
                bf16x8 av[4], bv[4];
#pragma unroll
                for (int m = 0; m < 4; ++m) {
                    av[m] = *(const bf16x8*)(As + cc * 6144 + rpA[m][dk] + cpA[m][dl]);
                    bv[m] = *(const bf16x8*)(Bs + cc * 6144 + rpB[m][dk] + cpB[m][dl]);
                }
#pragma unroll
                for (int m = 0; m < 4; ++m)
#pragma unroll
                    for (int c2 = 0; c2 < 4; ++c2)
                        acc[m][c2] = __builtin_amdgcn_mfma_f32_16x16x32_bf16(av[m], bv[c2], acc[m][c2], 0, 0, 0);
            }
    int hi = l >> 4;
#pragma unroll
    for (int m = 0; m < 4; ++m)
#pragma unroll
        for (int c2 = 0; c2 < 4; ++c2) {
            int q = q0 + wc * 64 + c2 * 16 + r;
            float fq = f[n * L + q];
#pragma unroll
            for (int reg = 0; reg < 4; ++reg) {
                int p = p0 + wr * 64 + m * 16 + hi * 4 + reg;
                float val = acc[m][c2][reg] * fq;
                if (p == q) val += PENALTY * unk[n * L + p];
                W[((size_t)n << 20) + ((size_t)p << 10) + q] = val;
            }
        }
}

// ---- row softmax over q (shuffle reductions); writes swizzled bf16 Wb ----
__global__ void k_softmax(const float* __restrict__ W, __bf16* __restrict__ Wb) {
    __shared__ float red[8];
    int row = blockIdx.x;  // n*L + p
    int p = row & (L - 1);
    const float* Wr = W + (size_t)row * 1024;
    __bf16* Wbr = Wb + (size_t)row * 1024;
    int t = threadIdx.x, wv = t >> 6;
    float v[4];
    float mx = -1e30f;
#pragma unroll
    for (int ll = 0; ll < 4; ++ll) {
        v[ll] = Wr[t + ll * 256];
        mx = fmaxf(mx, v[ll]);
    }
#pragma unroll
    for (int off = 32; off > 0; off >>= 1) mx = fmaxf(mx, __shfl_xor(mx, off));
    if ((t & 63) == 0) red[wv] = mx;
    __syncthreads();
    mx = fmaxf(fmaxf(red[0], red[1]), fmaxf(red[2], red[3]));
    float sum = 0.f;
#pragma unroll
    for (int ll = 0; ll < 4; ++ll) {
        v[ll] = __expf(v[ll] - mx);
        sum += v[ll];
    }
#pragma unroll
    for (int off = 32; off > 0; off >>= 1) sum += __shfl_xor(sum, off);
    if ((t & 63) == 0) red[4 + wv] = sum;
    __syncthreads();
    float inv = 1.0f / (red[4] + red[5] + red[6] + red[7]);
#pragma unroll
    for (int ll = 0; ll < 4; ++ll) Wbr[swz(t + ll * 256, p)] = (__bf16)(v[ll] * inv);
}

// ---- MFMA GEMM2: Tb[p][j] = sum_q W[p][q] * Bt[j][q].
// ---- 4-buffer BK=32 pipeline, counted vmcnt (T4): never drain to 0 mid-loop. ----
__global__ __launch_bounds__(256, 2) void k_gemm2(const __bf16* __restrict__ Wb,
                                                  const __bf16* __restrict__ Bt,
                                                  __bf16* __restrict__ Tb) {
    // bijective XCD-chunked remap: each XCD owns (n, p-half) -> L2-resident A panels
    int bid = blockIdx.x;
    int xcd = bid & 7, idx = bid >> 3;
    int n = xcd >> 1;
    int p0 = ((xcd & 1) * 4 + (idx & 3)) * 128;
    int j0 = (idx >> 2) * 128;
    __shared__ __align__(16) __bf16 As[4][4096];  // [buf][128 rows][32]
    __shared__ __align__(16) __bf16 Bs[4][4096];
    const __bf16* An = Wb + ((size_t)n << 20);
    const __bf16* Bn = Bt + ((size_t)n * NB << 10);
    int t = threadIdx.x, l = t & 63, w = t >> 6;
    int wr = w >> 1, wc = w & 1;
    int gl = l >> 4, r = l & 15;
    f32x4 acc[4][4] = {};

    auto stage = [&](int buf, int k0) {
#pragma unroll
        for (int i = 0; i < 2; ++i) {
            int row = (t >> 2) + i * 64;
            int sgo = (t & 3) * 8;
            const __bf16* srcA = An + ((size_t)(p0 + row) << 10) + k0 + sgo;
            __builtin_amdgcn_global_load_lds((gbl_t*)srcA, (lds_t*)(&As[buf][row * 32 + sgo]), 16, 0, 0);
            const __bf16* srcB = Bn + ((size_t)(j0 + row) << 10) + k0 + sgo;
            __builtin_amdgcn_global_load_lds((gbl_t*)srcB, (lds_t*)(&Bs[buf][row * 32 + sgo]), 16, 0, 0);
        }
    };
    auto compute = [&](int buf) {
        bf16x8 av[4], bv[4];
#pragma unroll
        for (int m = 0; m < 4; ++m) {
            int row = wr * 64 + m * 16 + r;
            av[m] = *(const bf16x8*)(&As[buf][row * 32 + ((gl ^ ((row >> 1) & 3)) << 3)]);
            int col = wc * 64 + m * 16 + r;
            bv[m] = *(const bf16x8*)(&Bs[buf][col * 32 + ((gl ^ ((col >> 1) & 3)) << 3)]);
        }
#pragma unroll
        for (int m = 0; m < 4; ++m)
#pragma unroll
            for (int c2 = 0; c2 < 4; ++c2)
                acc[m][c2] = __builtin_amdgcn_mfma_f32_16x16x32_bf16(av[m], bv[c2], acc[m][c2], 0, 0, 0);
    };

    stage(0, 0);
    stage(1, 32);
    for (int it = 0; it < 32; ++it) {
        int buf = it & 3;
        if (it + 2 < 32) stage((it + 2) & 3, (it + 2) * 32);
        // wait for buf `it`'s own 4 loads (each stage = 4 vmem ops/thread), then barrier
        if (it < 30)
            asm volatile("s_waitcnt vmcnt(8)\n\ts_barrier" ::: "memory");
        else if (it == 30)
            asm volatile("s_waitcnt vmcnt(4)\n\ts_barrier" ::: "memory");
        else
            asm volatile("s_waitcnt vmcnt(0)\n\ts_barrier" ::: "memory");
        compute(buf);
    }
    int hi = l >> 4;
#pragma unroll
    for (int m = 0; m < 4; ++m)
#pragma unroll
        for (int c2 = 0; c2 < 4; ++c2) {
            int j = j0 + wc * 64 + c2 * 16 + r;
#pragma unroll
            for (int reg = 0; reg < 4; ++reg) {
                int p = p0 + wr * 64 + m * 16 + hi * 4 + reg;
                Tb[((size_t)n * L + p) * NB + j] = (__bf16)acc[m][c2][reg];
            }
        }
}

// ---- gather of Tb taps -> prop[n][pix][swz(o,pix)] bf16, /4.
// ---- j' = ab*128+o layout makes each tap a contiguous bf16x8 load. ----
__global__ void k_gather(const __bf16* __restrict__ Tb, __bf16* __restrict__ prop) {
    int e = blockIdx.x * 256 + threadIdx.x;  // < 4*4096*16 = 262144
    int og = e & 15;
    int pix = (e >> 4) & 4095;
    int n = e >> 16;
    int x = pix & 63, y = pix >> 6;
    float acc[8] = {};
    int ap = (y + 1) & 1, bp = (x + 1) & 1;
    const __bf16* Tn = Tb + ((size_t)(n * L) << 11);
#pragma unroll
    for (int da = 0; da < 2; ++da) {
        int a = ap + 2 * da;
        int ny = y + 1 - a;
        if (ny < 0 || ny >= 64) continue;
        int py = ny >> 1;
#pragma unroll
        for (int db = 0; db < 2; ++db) {
            int bb = bp + 2 * db;
            int nx = x + 1 - bb;
            if (nx < 0 || nx >= 64) continue;
            int px = nx >> 1;
            bf16x8 v = *(const bf16x8*)(Tn + (((size_t)(py * hh + px)) << 11) + (a * 4 + bb) * 128 + og * 8);
#pragma unroll
            for (int u2 = 0; u2 < 8; ++u2) acc[u2] += (float)v[u2];
        }
    }
    __bf16 rr[8];
#pragma unroll
    for (int u2 = 0; u2 < 8; ++u2) rr[u2] = (__bf16)(acc[u2] * 0.25f);
    int dg = og ^ ((pix >> 1) & 3);
    *(bf16x8*)(prop + ((((size_t)(n << 12) + pix)) << 7) + dg * 8) = *(bf16x8*)rr;
}

// ---- MFMA oconv: y2[n][j][pix] = sum_o ow[j][o] * prop[n][pix][o], f32 NCHW out ----
__global__ __launch_bounds__(256, 2) void k_oconv(const __bf16* __restrict__ owb,
                                                  const __bf16* __restrict__ prop,
                                                  float* __restrict__ y2) {
    __shared__ __align__(16) __bf16 As[128 * 32];
    __shared__ __align__(16) __bf16 Bs[128 * 32];
    int n = blockIdx.z;
    int x0 = blockIdx.x * 128;
    const __bf16* Bn = prop + ((size_t)n << 19);
    int t = threadIdx.x, l = t & 63, w = t >> 6;
    int wr = w >> 1, wc = w & 1;
    f32x4 acc[4][4] = {};
    for (int k0 = 0; k0 < CH; k0 += 32) {
#pragma unroll
        for (int i = 0; i < 2; ++i) {
            const __bf16* srcA = owb + (size_t)(i * 64 + (t >> 2)) * CH + k0 + (t & 3) * 8;
            __builtin_amdgcn_global_load_lds((gbl_t*)srcA, (lds_t*)(As + i * 2048 + t * 8), 16, 0, 0);
            const __bf16* srcB = Bn + (size_t)(x0 + i * 64 + (t >> 2)) * CH + k0 + (t & 3) * 8;
            __builtin_amdgcn_global_load_lds((gbl_t*)srcB, (lds_t*)(Bs + i * 2048 + t * 8), 16, 0, 0);
        }
        __syncthreads();
        int gl = l >> 4, r = l & 15;
        bf16x8 av[4], bv[4];
#pragma unroll
        for (int m = 0; m < 4; ++m) {
            int row = wr * 64 + m * 16 + r;
            av[m] = *(const bf16x8*)(As + row * 32 + swz(gl << 3, row));
            int col = x0 + wc * 64 + m * 16 + r;
            bv[m] = *(const bf16x8*)(Bs + (wc * 64 + m * 16 + r) * 32 + swz(gl << 3, col));
        }
#pragma unroll
        for (int m = 0; m < 4; ++m)
#pragma unroll
            for (int c2 = 0; c2 < 4; ++c2)
                acc[m][c2] = __builtin_amdgcn_mfma_f32_16x16x32_bf16(av[m], bv[c2], acc[m][c2], 0, 0, 0);
        __syncthreads();
    }
    int r = l & 15, hi = l >> 4;
#pragma unroll
    for (int m = 0; m < 4; ++m)
#pragma unroll
        for (int c2 = 0; c2 < 4; ++c2) {
            int pix = x0 + wc * 64 + c2 * 16 + r;
#pragma unroll
            for (int reg = 0; reg < 4; ++reg) {
                int j = wr * 64 + m * 16 + hi * 4 + reg;
                y2[(((size_t)n * CH + j) << 12) + pix] = acc[m][c2][reg];
            }
        }
}

// ---- per-channel BN stats (deterministic two-stage) ----
__global__ void k_bnstats(const float* __restrict__ y2, float* __restrict__ stats) {
    __shared__ float r1[256], r2[256];
    int oc = blockIdx.x, t = threadIdx.x;
    float s = 0.f, s2 = 0.f;
    for (int n = 0; n < NN; ++n) {
        const float* base = y2 + (((size_t)n * CH + oc) << 12);
        for (int pix = t; pix < 4096; pix += 256) {
            float v = base[pix];
            s += v;
            s2 += v * v;
        }
    }
    r1[t] = s;
    r2[t] = s2;
    __syncthreads();
    for (int st = 128; st > 0; st >>= 1) {
        if (t < st) {
            r1[t] += r1[t + st];
            r2[t] += r2[t + st];
        }
        __syncthreads();
    }
    if (t == 0) {
        stats[oc * 2] = r1[0];
        stats[oc * 2 + 1] = r2[0];
    }
}

// ---- BN normalize + residual ----
__global__ void k_final(const float* __restrict__ y2, const float* __restrict__ stats,
                        const float* __restrict__ gamma, const float* __restrict__ beta,
                        const float* __restrict__ alpha, float* __restrict__ out) {
    int e = blockIdx.x * 256 + threadIdx.x;
    int oc = (e >> 12) & 127;
    float s1 = stats[oc * 2], s2 = stats[oc * 2 + 1];
    float mu = s1 * (1.0f / 16384.0f);
    float var = s2 * (1.0f / 16384.0f) - mu * mu;
    float inv = rsqrtf(var + 1e-5f);
    out[e] = (y2[e] - mu) * inv * gamma[oc] + beta[oc] + alpha[e];
}

extern "C" void kernel_launch(void* const* d_in, const int* in_sizes, int n_in,
                              void* d_out, int out_size, void* d_ws, size_t ws_size,
                              hipStream_t stream) {
    const float* img = (const float*)d_in[0];
    const float* alpha = (const float*)d_in[1];
    const float* unknown = (const float*)d_in[2];
    const float* gw = (const float*)d_in[3];
    const float* gb = (const float*)d_in[4];
    const float* ow = (const float*)d_in[5];
    const float* gamma = (const float*)d_in[6];
    const float* beta = (const float*)d_in[7];
    float* out = (float*)d_out;
    float* ws = (float*)d_ws;

    // layout (float-word offsets)
    __bf16* Xb = (__bf16*)(ws);                // 524288 fw
    __bf16* gwb = (__bf16*)(ws + 524288);      // 16384 fw
    __bf16* owb = (__bf16*)(ws + 540672);      // 8192 fw
    __bf16* gbf = (__bf16*)(ws + 548864);      // 262144 fw  (4096x128 bf16)
    float* f = ws + 811008;                    // 4096
    float* unk = ws + 815104;                  // 4096
    float* scales = ws + 819200;               // 64
    float* stats = ws + 819264;                // 256
    float* W = ws + 819520;                    // 4194304 fw
    __bf16* Wb = (__bf16*)(ws + 5013824);      // 2097152 fw
    __bf16* Bt = (__bf16*)(ws + 7110976);      // 4194304 fw
    __bf16* Tb = (__bf16*)(ws + 11305280);     // 4194304 fw
    __bf16* prop = (__bf16*)(ws + 15499584);   // 1048576 fw
    float* y2 = ws + 16548160;                 // 2097152 fw
    // total 18,645,312 fw ≈ 74.6 MB

    k_prep<<<168, 256, 0, stream>>>(img, gw, ow, unknown, Xb, gwb, owb, unk, scales);
    k_btbuild<<<512, 256, 0, stream>>>(alpha, Bt);
    k_gemm0<<<32, 256, 0, stream>>>(Xb, gwb, gb, gbf);
    k_ssqf<<<4, 256, 0, stream>>>(gbf, unk, scales, f);
    k_gemm1<<<dim3(8, 8, 4), 256, 0, stream>>>(gbf, f, unk, W);
    k_softmax<<<4096, 256, 0, stream>>>(W, Wb);
    k_gemm2<<<512, 256, 0, stream>>>(Wb, Bt, Tb);
    k_gather<<<1024, 256, 0, stream>>>(Tb, prop);
    k_oconv<<<dim3(32, 1, 4), 256, 0, stream>>>(owb, prop, y2);
    k_bnstats<<<128, 256, 0, stream>>>(y2, stats);
    k_final<<<8192, 256, 0, stream>>>(y2, stats, gamma, beta, alpha, out);
}

// Round 3
// 102.712 us; speedup vs baseline: 1.4489x; 1.1078x over previous
//
#include <hip/hip_runtime.h>

#define NN 4
#define CIN 256
#define CH 128       // gconv out channels = AC = oconv channels
#define HH 64
#define hh 32
#define L 1024
#define NB 2048      // CH*16
#define PENALTY -10000.0f
#define EPS 1e-4f

typedef __bf16 bf16x8 __attribute__((ext_vector_type(8)));
typedef float f32x4 __attribute__((ext_vector_type(4)));
typedef __attribute__((address_space(3))) void lds_t;
typedef __attribute__((address_space(1))) const void gbl_t;

__device__ __forceinline__ int refl32(int t) { return t < 0 ? -t : (t > 31 ? 62 - t : t); }
__device__ __forceinline__ int refl64(int t) { return t < 0 ? -t : (t > 63 ? 126 - t : t); }
// XOR-swizzle of element index (16B/8-elem granule) within a 32-elem K-chunk, keyed by row
__device__ __forceinline__ int swz(int k, int row) { return k ^ (((row >> 1) & 3) << 3); }

// ---- fused prep: alpha->Bt patches (blocks 0..511), img downsample+transpose
// ---- (512..639), unknown stats (640..643), weight convert + stats-zero (644..679) ----
__global__ void k_prep(const float* __restrict__ img, const float* __restrict__ gw,
                       const float* __restrict__ ow, const float* __restrict__ unknown,
                       const float* __restrict__ alpha,
                       __bf16* __restrict__ Xb, __bf16* __restrict__ gwb,
                       __bf16* __restrict__ owb, float* __restrict__ unk,
                       float* __restrict__ scales, __bf16* __restrict__ Bt,
                       float* __restrict__ stats) {
    __shared__ float sm[CIN * 33];
    int bid = blockIdx.x, t = threadIdx.x;
    if (bid < 512) {
        // btbuild: one block per (n,o): stage alpha plane (coalesced), emit 16 ab rows.
        int n = bid >> 7, o = bid & 127;
        const float* ap = alpha + ((size_t)(n * CH + o) << 12);
#pragma unroll
        for (int j = 0; j < 4; ++j) {
            int fi = t + j * 256;      // float4 index 0..1023
            int row = fi >> 4, c4 = fi & 15;
            float4 v = *(const float4*)(ap + fi * 4);
            float* d = sm + row * 65 + c4 * 4;
            d[0] = v.x; d[1] = v.y; d[2] = v.z; d[3] = v.w;
        }
        __syncthreads();
        __bf16* Bn = Bt + ((size_t)(n * NB) << 10);
#pragma unroll
        for (int gi = 0; gi < 8; ++gi) {
            int g = gi * 256 + t;      // granule 0..2047
            int ab = g >> 7, qg = g & 127;
            int a = ab >> 2, bb = ab & 3;
            int q0 = qg * 8;
            int qi = q0 >> 5, qj0 = q0 & 31;
            int ti = refl64(2 * qi + a - 1);
            const float* r = sm + ti * 65;
            __bf16 v[8];
#pragma unroll
            for (int s = 0; s < 8; ++s) v[s] = (__bf16)r[refl64(2 * (qj0 + s) + bb - 1)];
            int j = ab * 128 + o;
            *(bf16x8*)(Bn + ((size_t)j << 10) + swz(q0, j)) = *(bf16x8*)v;
        }
    } else if (bid < 640) {
        // prep_x: downsample img, transpose to [np][c], pre-swizzled bf16
        int idx = bid - 512;
        int i = idx & 31, n = idx >> 5;
        for (int e = t; e < CIN * 32; e += 256) {
            int c = e >> 5, jj = e & 31;
            sm[c * 33 + jj] = img[(((size_t)n * CIN + c) * HH + 2 * i) * HH + 2 * jj];
        }
        __syncthreads();
#pragma unroll
        for (int j = 0; j < 32; ++j) {
            int np = (n << 10) + i * 32 + j;
            int cl = swz(t, np);
            Xb[(size_t)np * CIN + t] = (__bf16)sm[cl * 33 + j];
        }
    } else if (bid < 644) {
        // stats: unknown downsample, mean -> scales, 3x3 reflect box mean -> unk
        int n = bid - 640;
        float* u = sm;            // [1024]
        float* red = sm + 1024;   // [256]
        float part = 0.f;
#pragma unroll
        for (int c = 0; c < 4; ++c) {
            int idx = t + c * 256;
            int i = idx >> 5, j = idx & 31;
            float v = unknown[n * 4096 + (2 * i) * HH + 2 * j];
            u[idx] = v;
            part += v;
        }
        red[t] = part;
        __syncthreads();
        for (int s = 128; s > 0; s >>= 1) {
            if (t < s) red[t] += red[t + s];
            __syncthreads();
        }
        if (t == 0) {
            float um = red[0] / 1024.0f;
            float km = 1.0f - um;
            scales[n * 2] = fminf(fmaxf(sqrtf(um / km), 0.1f), 10.0f);
            scales[n * 2 + 1] = fminf(fmaxf(sqrtf(km / um), 0.1f), 10.0f);
        }
#pragma unroll
        for (int c = 0; c < 4; ++c) {
            int idx = t + c * 256;
            int i = idx >> 5, j = idx & 31;
            float sum = 0.f;
#pragma unroll
            for (int di = -1; di <= 1; ++di)
#pragma unroll
                for (int dj = -1; dj <= 1; ++dj)
                    sum += u[refl32(i + di) * 32 + refl32(j + dj)];
            unk[n * L + idx] = sum * (1.0f / 9.0f);
        }
    } else {
        // prep_w: weights -> bf16 pre-swizzled; block 644 zeros BN stats accumulator
        if (bid == 644) stats[t] = 0.f;
        for (int e = (bid - 644) * 256 + t; e < 49152; e += 36 * 256) {
            if (e < 32768) {
                int o = e >> 8, m = e & 255;
                gwb[e] = (__bf16)gw[o * 256 + swz(m, o)];
            } else {
                int e2 = e - 32768;
                int j = e2 >> 7, m = e2 & 127;
                owb[e2] = (__bf16)ow[j * 128 + swz(m, j)];
            }
        }
    }
}

// ---- MFMA GEMM0: gbf[np][o] = Xb . gwb^T + gb, bf16 out ----
__global__ __launch_bounds__(256, 2) void k_gemm0(const __bf16* __restrict__ Xb,
                                                  const __bf16* __restrict__ gwb,
                                                  const float* __restrict__ gb,
                                                  __bf16* __restrict__ gbf) {
    __shared__ __align__(16) __bf16 As[128 * 32];
    __shared__ __align__(16) __bf16 Bs[128 * 32];
    int p0 = blockIdx.x * 128;
    int t = threadIdx.x, l = t & 63, w = t >> 6;
    int wr = w >> 1, wc = w & 1;
    f32x4 acc[4][4] = {};
    for (int k0 = 0; k0 < CIN; k0 += 32) {
#pragma unroll
        for (int i = 0; i < 2; ++i) {
            const __bf16* srcA = Xb + (size_t)(p0 + i * 64 + (t >> 2)) * CIN + k0 + (t & 3) * 8;
            __builtin_amdgcn_global_load_lds((gbl_t*)srcA, (lds_t*)(As + i * 2048 + t * 8), 16, 0, 0);
            const __bf16* srcB = gwb + (size_t)(i * 64 + (t >> 2)) * CIN + k0 + (t & 3) * 8;
            __builtin_amdgcn_global_load_lds((gbl_t*)srcB, (lds_t*)(Bs + i * 2048 + t * 8), 16, 0, 0);
        }
        __syncthreads();
        int gl = l >> 4, r = l & 15;
        bf16x8 av[4], bv[4];
#pragma unroll
        for (int m = 0; m < 4; ++m) {
            int row = wr * 64 + m * 16 + r;
            av[m] = *(const bf16x8*)(As + row * 32 + swz(gl << 3, row));
            int col = wc * 64 + m * 16 + r;
            bv[m] = *(const bf16x8*)(Bs + col * 32 + swz(gl << 3, col));
        }
#pragma unroll
        for (int m = 0; m < 4; ++m)
#pragma unroll
            for (int c2 = 0; c2 < 4; ++c2)
                acc[m][c2] = __builtin_amdgcn_mfma_f32_16x16x32_bf16(av[m], bv[c2], acc[m][c2], 0, 0, 0);
        __syncthreads();
    }
    int r = l & 15, hi = l >> 4;
#pragma unroll
    for (int m = 0; m < 4; ++m)
#pragma unroll
        for (int c2 = 0; c2 < 4; ++c2) {
            int o = wc * 64 + c2 * 16 + r;
            float bias = gb[o];
#pragma unroll
            for (int reg = 0; reg < 4; ++reg) {
                int row = p0 + wr * 64 + m * 16 + hi * 4 + reg;
                gbf[((size_t)row << 7) + o] = (__bf16)(acc[m][c2][reg] + bias);
            }
        }
}

// ---- fused ssq + normf: per-row ssq of gbf (LDS), 3x3 sum, f[q]. 1024 threads. ----
__global__ void k_ssqf(const __bf16* __restrict__ gbf, const float* __restrict__ unk,
                       const float* __restrict__ scales, float* __restrict__ f) {
    __shared__ float ssqs[1024];
    int n = blockIdx.x, t = threadIdx.x;  // t < 1024
    {
        const __bf16* rp = gbf + (((size_t)(n << 10) + t) << 7);
        float s = 0.f;
#pragma unroll
        for (int kk = 0; kk < 16; ++kk) {
            bf16x8 v = *(const bf16x8*)(rp + kk * 8);
#pragma unroll
            for (int u2 = 0; u2 < 8; ++u2) {
                float x = (float)v[u2];
                s += x * x;
            }
        }
        ssqs[t] = s;
    }
    __syncthreads();
    float us = scales[n * 2], ks = scales[n * 2 + 1];
    int pi = t >> 5, pj = t & 31;
    float sum = 0.f;
#pragma unroll
    for (int di = -1; di <= 1; ++di)
#pragma unroll
        for (int dj = -1; dj <= 1; ++dj)
            sum += ssqs[refl32(pi + di) * 32 + refl32(pj + dj)];
    float norm = sqrtf(sum);
    float sc = unk[n * L + t] > 0.f ? us : ks;
    f[n * L + t] = sc / fmaxf(norm, EPS);
}

// ---- MFMA GEMM1: whole 6x32-row gbf window (3x3 taps + reflect halo) staged
// ---- to LDS once; 576 MFMAs barrier-free. LDS chunk-major [4][192][32]. ----
__global__ __launch_bounds__(256, 1) void k_gemm1(const __bf16* __restrict__ gbf,
                                                  const float* __restrict__ f,
                                                  const float* __restrict__ unk,
                                                  float* __restrict__ W) {
    __shared__ __align__(16) __bf16 As[4 * 6144];  // [chunk][192 rows][32]
    __shared__ __align__(16) __bf16 Bs[4 * 6144];
    int n = blockIdx.z;
    int p0 = blockIdx.y * 128, q0 = blockIdx.x * 128;
    const __bf16* gn = gbf + ((size_t)n << 17);
    int t = threadIdx.x, l = t & 63, w = t >> 6;
    int wr = w >> 1, wc = w & 1;
    int by4 = blockIdx.y * 4, bx4 = blockIdx.x * 4;
    int rbA = by4 - 1; rbA = rbA < 0 ? 0 : (rbA > 26 ? 26 : rbA);
    int rbB = bx4 - 1; rbB = rbB < 0 ? 0 : (rbB > 26 ? 26 : rbB);
#pragma unroll
    for (int k = 0; k < 12; ++k) {
        int chunk = k / 3;
        int rem = (k % 3) * 256 + t;           // granule within chunk-plane [0,768)
        int wrow = rem >> 2, sg = rem & 3;
        int so = (chunk << 5) + ((sg ^ ((wrow >> 1) & 3)) << 3);
        int grA = ((rbA + (wrow >> 5)) << 5) + (wrow & 31);
        __builtin_amdgcn_global_load_lds((gbl_t*)(gn + (size_t)grA * 128 + so),
                                         (lds_t*)(As + chunk * 6144 + rem * 8), 16, 0, 0);
        int grB = ((rbB + (wrow >> 5)) << 5) + (wrow & 31);
        __builtin_amdgcn_global_load_lds((gbl_t*)(gn + (size_t)grB * 128 + so),
                                         (lds_t*)(Bs + chunk * 6144 + rem * 8), 16, 0, 0);
    }
    __syncthreads();
    int gl = l >> 4, r = l & 15;
    int rpA[4][3], cpA[4][3], rpB[4][3], cpB[4][3];
#pragma unroll
    for (int m = 0; m < 4; ++m) {
        int prow = wr * 64 + m * 16 + r;
        int qrow = wc * 64 + m * 16 + r;
#pragma unroll
        for (int d = 0; d < 3; ++d) {
            rpA[m][d] = (refl32(by4 + (prow >> 5) + d - 1) - rbA) << 10;
            int cp = refl32((prow & 31) + d - 1);
            cpA[m][d] = cp * 32 + ((gl ^ ((cp >> 1) & 3)) << 3);
            rpB[m][d] = (refl32(bx4 + (qrow >> 5) + d - 1) - rbB) << 10;
            int cq = refl32((qrow & 31) + d - 1);
            cpB[m][d] = cq * 32 + ((gl ^ ((cq >> 1) & 3)) << 3);
        }
    }
    f32x4 acc[4][4] = {};
#pragma unroll
    for (int dk = 0; dk < 3; ++dk)
#pragma unroll
        for (int dl = 0; dl < 3; ++dl)
#pragma unroll
            for (int cc = 0; cc < 4; ++cc) {
                bf16x8 av[4], bv[4];
#pragma unroll
                for (int m = 0; m < 4; ++m) {
                    av[m] = *(const bf16x8*)(As + cc * 6144 + rpA[m][dk] + cpA[m][dl]);
                    bv[m] = *(const bf16x8*)(Bs + cc * 6144 + rpB[m][dk] + cpB[m][dl]);
                }
#pragma unroll
                for (int m = 0; m < 4; ++m)
#pragma unroll
                    for (int c2 = 0; c2 < 4; ++c2)
                        acc[m][c2] = __builtin_amdgcn_mfma_f32_16x16x32_bf16(av[m], bv[c2], acc[m][c2], 0, 0, 0);
            }
    int hi = l >> 4;
#pragma unroll
    for (int m = 0; m < 4; ++m)
#pragma unroll
        for (int c2 = 0; c2 < 4; ++c2) {
            int q = q0 + wc * 64 + c2 * 16 + r;
            float fq = f[n * L + q];
#pragma unroll
            for (int reg = 0; reg < 4; ++reg) {
                int p = p0 + wr * 64 + m * 16 + hi * 4 + reg;
                float val = acc[m][c2][reg] * fq;
                if (p == q) val += PENALTY * unk[n * L + p];
                W[((size_t)n << 20) + ((size_t)p << 10) + q] = val;
            }
        }
}

// ---- row softmax over q (shuffle reductions); writes swizzled bf16 Wb ----
__global__ void k_softmax(const float* __restrict__ W, __bf16* __restrict__ Wb) {
    __shared__ float red[8];
    int row = blockIdx.x;  // n*L + p
    int p = row & (L - 1);
    const float* Wr = W + (size_t)row * 1024;
    __bf16* Wbr = Wb + (size_t)row * 1024;
    int t = threadIdx.x, wv = t >> 6;
    float v[4];
    float mx = -1e30f;
#pragma unroll
    for (int ll = 0; ll < 4; ++ll) {
        v[ll] = Wr[t + ll * 256];
        mx = fmaxf(mx, v[ll]);
    }
#pragma unroll
    for (int off = 32; off > 0; off >>= 1) mx = fmaxf(mx, __shfl_xor(mx, off));
    if ((t & 63) == 0) red[wv] = mx;
    __syncthreads();
    mx = fmaxf(fmaxf(red[0], red[1]), fmaxf(red[2], red[3]));
    float sum = 0.f;
#pragma unroll
    for (int ll = 0; ll < 4; ++ll) {
        v[ll] = __expf(v[ll] - mx);
        sum += v[ll];
    }
#pragma unroll
    for (int off = 32; off > 0; off >>= 1) sum += __shfl_xor(sum, off);
    if ((t & 63) == 0) red[4 + wv] = sum;
    __syncthreads();
    float inv = 1.0f / (red[4] + red[5] + red[6] + red[7]);
#pragma unroll
    for (int ll = 0; ll < 4; ++ll) Wbr[swz(t + ll * 256, p)] = (__bf16)(v[ll] * inv);
}

// ---- MFMA GEMM2: Tb[p][j] = sum_q W[p][q] * Bt[j][q].
// ---- 4-buffer BK=32 pipeline, counted vmcnt (T4): never drain to 0 mid-loop. ----
__global__ __launch_bounds__(256, 2) void k_gemm2(const __bf16* __restrict__ Wb,
                                                  const __bf16* __restrict__ Bt,
                                                  __bf16* __restrict__ Tb) {
    int bid = blockIdx.x;
    int xcd = bid & 7, idx = bid >> 3;
    int n = xcd >> 1;
    int p0 = ((xcd & 1) * 4 + (idx & 3)) * 128;
    int j0 = (idx >> 2) * 128;
    __shared__ __align__(16) __bf16 As[4][4096];  // [buf][128 rows][32]
    __shared__ __align__(16) __bf16 Bs[4][4096];
    const __bf16* An = Wb + ((size_t)n << 20);
    const __bf16* Bn = Bt + ((size_t)n * NB << 10);
    int t = threadIdx.x, l = t & 63, w = t >> 6;
    int wr = w >> 1, wc = w & 1;
    int gl = l >> 4, r = l & 15;
    f32x4 acc[4][4] = {};

    auto stage = [&](int buf, int k0) {
#pragma unroll
        for (int i = 0; i < 2; ++i) {
            int row = (t >> 2) + i * 64;
            int sgo = (t & 3) * 8;
            const __bf16* srcA = An + ((size_t)(p0 + row) << 10) + k0 + sgo;
            __builtin_amdgcn_global_load_lds((gbl_t*)srcA, (lds_t*)(&As[buf][row * 32 + sgo]), 16, 0, 0);
            const __bf16* srcB = Bn + ((size_t)(j0 + row) << 10) + k0 + sgo;
            __builtin_amdgcn_global_load_lds((gbl_t*)srcB, (lds_t*)(&Bs[buf][row * 32 + sgo]), 16, 0, 0);
        }
    };
    auto compute = [&](int buf) {
        bf16x8 av[4], bv[4];
#pragma unroll
        for (int m = 0; m < 4; ++m) {
            int row = wr * 64 + m * 16 + r;
            av[m] = *(const bf16x8*)(&As[buf][row * 32 + ((gl ^ ((row >> 1) & 3)) << 3)]);
            int col = wc * 64 + m * 16 + r;
            bv[m] = *(const bf16x8*)(&Bs[buf][col * 32 + ((gl ^ ((col >> 1) & 3)) << 3)]);
        }
#pragma unroll
        for (int m = 0; m < 4; ++m)
#pragma unroll
            for (int c2 = 0; c2 < 4; ++c2)
                acc[m][c2] = __builtin_amdgcn_mfma_f32_16x16x32_bf16(av[m], bv[c2], acc[m][c2], 0, 0, 0);
    };

    stage(0, 0);
    stage(1, 32);
    for (int it = 0; it < 32; ++it) {
        int buf = it & 3;
        if (it + 2 < 32) stage((it + 2) & 3, (it + 2) * 32);
        if (it < 30)
            asm volatile("s_waitcnt vmcnt(8)\n\ts_barrier" ::: "memory");
        else if (it == 30)
            asm volatile("s_waitcnt vmcnt(4)\n\ts_barrier" ::: "memory");
        else
            asm volatile("s_waitcnt vmcnt(0)\n\ts_barrier" ::: "memory");
        compute(buf);
    }
    int hi = l >> 4;
#pragma unroll
    for (int m = 0; m < 4; ++m)
#pragma unroll
        for (int c2 = 0; c2 < 4; ++c2) {
            int j = j0 + wc * 64 + c2 * 16 + r;
#pragma unroll
            for (int reg = 0; reg < 4; ++reg) {
                int p = p0 + wr * 64 + m * 16 + hi * 4 + reg;
                Tb[((size_t)n * L + p) * NB + j] = (__bf16)acc[m][c2][reg];
            }
        }
}

// ---- fused gather + oconv + BN partials:
// ---- phase1: build prop B-panel (64 pix x 128 o) in LDS from Tb taps; stage all owb.
// ---- phase2: 4-chunk barrier-free MFMA. epilogue: y2 + BN partial atomics. ----
__global__ void k_oconv(const __bf16* __restrict__ owb, const __bf16* __restrict__ Tb,
                        float* __restrict__ y2, float* __restrict__ stats) {
    __shared__ __align__(16) __bf16 As[4 * 4096];  // [chunk][128 j][32]
    __shared__ __align__(16) __bf16 Bp[4 * 2048];  // [chunk][64 pix][32]
    int n = blockIdx.z;
    int x0 = blockIdx.x * 64;
    int t = threadIdx.x, l = t & 63, w = t >> 6;
    int wr = w >> 1, wc = w & 1;
    int gl = l >> 4, r = l & 15, hi = l >> 4;
    // stage all of owb chunk-major: As[c][j][sgl*8] = owb[j][c*32+sgl*8]
#pragma unroll
    for (int c = 0; c < 4; ++c)
#pragma unroll
        for (int i = 0; i < 2; ++i) {
            int h = i * 256 + t;          // [0,512): j = h>>2, sgl = h&3
            const __bf16* src = owb + (size_t)(h >> 2) * CH + c * 32 + (h & 3) * 8;
            __builtin_amdgcn_global_load_lds((gbl_t*)src, (lds_t*)(As + c * 4096 + h * 8), 16, 0, 0);
        }
    // gather phase: 1024 tasks (64 pix x 16 og granules), 4 per thread
    const __bf16* Tn = Tb + ((size_t)(n * L) << 11);
#pragma unroll
    for (int it = 0; it < 4; ++it) {
        int e2 = it * 256 + t;
        int og = e2 & 15, pl = e2 >> 4;   // pl in [0,64)
        int pix = x0 + pl;
        int x = pix & 63, y = pix >> 6;
        float acc8[8] = {};
        int ap = (y + 1) & 1, bp = (x + 1) & 1;
#pragma unroll
        for (int da = 0; da < 2; ++da) {
            int a = ap + 2 * da;
            int ny = y + 1 - a;
            if (ny < 0 || ny >= 64) continue;
            int py = ny >> 1;
#pragma unroll
            for (int db = 0; db < 2; ++db) {
                int bb = bp + 2 * db;
                int nx = x + 1 - bb;
                if (nx < 0 || nx >= 64) continue;
                int px = nx >> 1;
                bf16x8 v = *(const bf16x8*)(Tn + (((size_t)(py * hh + px)) << 11) + (a * 4 + bb) * 128 + og * 8);
#pragma unroll
                for (int u2 = 0; u2 < 8; ++u2) acc8[u2] += (float)v[u2];
            }
        }
        __bf16 rr[8];
#pragma unroll
        for (int u2 = 0; u2 < 8; ++u2) rr[u2] = (__bf16)(acc8[u2] * 0.25f);
        int key = (pix >> 1) & 3;
        int dgl = (og & 3) ^ key;
        *(bf16x8*)(Bp + (og >> 2) * 2048 + pl * 32 + dgl * 8) = *(bf16x8*)rr;
    }
    __syncthreads();
    // compute: 4 chunks, no barriers; acc[m][c2]: j = wr*64+m*16.., pix = wc*32+c2*16..
    f32x4 acc[4][2] = {};
#pragma unroll
    for (int c = 0; c < 4; ++c) {
        bf16x8 av[4], bv[2];
#pragma unroll
        for (int m = 0; m < 4; ++m) {
            int row = wr * 64 + m * 16 + r;
            av[m] = *(const bf16x8*)(As + c * 4096 + row * 32 + ((gl ^ ((row >> 1) & 3)) << 3));
        }
#pragma unroll
        for (int c2 = 0; c2 < 2; ++c2) {
            int col = wc * 32 + c2 * 16 + r;   // local pix; global key == local key
            bv[c2] = *(const bf16x8*)(Bp + c * 2048 + col * 32 + ((gl ^ ((col >> 1) & 3)) << 3));
        }
#pragma unroll
        for (int m = 0; m < 4; ++m)
#pragma unroll
            for (int c2 = 0; c2 < 2; ++c2)
                acc[m][c2] = __builtin_amdgcn_mfma_f32_16x16x32_bf16(av[m], bv[c2], acc[m][c2], 0, 0, 0);
    }
    // epilogue: y2 writes
#pragma unroll
    for (int m = 0; m < 4; ++m)
#pragma unroll
        for (int c2 = 0; c2 < 2; ++c2) {
            int pix = x0 + wc * 32 + c2 * 16 + r;
#pragma unroll
            for (int reg = 0; reg < 4; ++reg) {
                int j = wr * 64 + m * 16 + hi * 4 + reg;
                y2[(((size_t)n * CH + j) << 12) + pix] = acc[m][c2][reg];
            }
        }
    // BN partials: reduce over r (16-lane groups), then [j][wc] LDS, then atomics
    __syncthreads();  // done reading As/Bp; reuse As as float scratch
    float* partS = (float*)As;        // [128][2]
    float* partS2 = partS + 256;      // [128][2]
#pragma unroll
    for (int m = 0; m < 4; ++m)
#pragma unroll
        for (int reg = 0; reg < 4; ++reg) {
            float s = 0.f, s2 = 0.f;
#pragma unroll
            for (int c2 = 0; c2 < 2; ++c2) {
                float v = acc[m][c2][reg];
                s += v;
                s2 += v * v;
            }
#pragma unroll
            for (int off = 1; off < 16; off <<= 1) {
                s += __shfl_xor(s, off);
                s2 += __shfl_xor(s2, off);
            }
            if (r == 0) {
                int j = wr * 64 + m * 16 + hi * 4 + reg;
                partS[j * 2 + wc] = s;
                partS2[j * 2 + wc] = s2;
            }
        }
    __syncthreads();
    if (t < 128) {
        atomicAdd(&stats[t * 2], partS[t * 2] + partS[t * 2 + 1]);
        atomicAdd(&stats[t * 2 + 1], partS2[t * 2] + partS2[t * 2 + 1]);
    }
}

// ---- BN normalize + residual (float4) ----
__global__ void k_final(const float* __restrict__ y2, const float* __restrict__ stats,
                        const float* __restrict__ gamma, const float* __restrict__ beta,
                        const float* __restrict__ alpha, float* __restrict__ out) {
    int e4 = blockIdx.x * 256 + threadIdx.x;  // < 524288 float4s
    int oc = (e4 >> 10) & 127;
    float s1 = stats[oc * 2], s2 = stats[oc * 2 + 1];
    float mu = s1 * (1.0f / 16384.0f);
    float var = s2 * (1.0f / 16384.0f) - mu * mu;
    float inv = rsqrtf(var + 1e-5f);
    float g = gamma[oc], b = beta[oc];
    float4 yv = ((const float4*)y2)[e4];
    float4 av = ((const float4*)alpha)[e4];
    float4 o;
    o.x = (yv.x - mu) * inv * g + b + av.x;
    o.y = (yv.y - mu) * inv * g + b + av.y;
    o.z = (yv.z - mu) * inv * g + b + av.z;
    o.w = (yv.w - mu) * inv * g + b + av.w;
    ((float4*)out)[e4] = o;
}

extern "C" void kernel_launch(void* const* d_in, const int* in_sizes, int n_in,
                              void* d_out, int out_size, void* d_ws, size_t ws_size,
                              hipStream_t stream) {
    const float* img = (const float*)d_in[0];
    const float* alpha = (const float*)d_in[1];
    const float* unknown = (const float*)d_in[2];
    const float* gw = (const float*)d_in[3];
    const float* gb = (const float*)d_in[4];
    const float* ow = (const float*)d_in[5];
    const float* gamma = (const float*)d_in[6];
    const float* beta = (const float*)d_in[7];
    float* out = (float*)d_out;
    float* ws = (float*)d_ws;

    // layout (float-word offsets)
    __bf16* Xb = (__bf16*)(ws);                // 524288 fw
    __bf16* gwb = (__bf16*)(ws + 524288);      // 16384 fw
    __bf16* owb = (__bf16*)(ws + 540672);      // 8192 fw
    __bf16* gbf = (__bf16*)(ws + 548864);      // 262144 fw  (4096x128 bf16)
    float* f = ws + 811008;                    // 4096
    float* unk = ws + 815104;                  // 4096
    float* scales = ws + 819200;               // 64
    float* stats = ws + 819264;                // 256
    float* W = ws + 819520;                    // 4194304 fw
    __bf16* Wb = (__bf16*)(ws + 5013824);      // 2097152 fw
    __bf16* Bt = (__bf16*)(ws + 7110976);      // 4194304 fw
    __bf16* Tb = (__bf16*)(ws + 11305280);     // 4194304 fw
    float* y2 = ws + 15499584;                 // 2097152 fw
    // total ~70 MB

    k_prep<<<680, 256, 0, stream>>>(img, gw, ow, unknown, alpha, Xb, gwb, owb, unk, scales, Bt, stats);
    k_gemm0<<<32, 256, 0, stream>>>(Xb, gwb, gb, gbf);
    k_ssqf<<<4, 1024, 0, stream>>>(gbf, unk, scales, f);
    k_gemm1<<<dim3(8, 8, 4), 256, 0, stream>>>(gbf, f, unk, W);
    k_softmax<<<4096, 256, 0, stream>>>(W, Wb);
    k_gemm2<<<512, 256, 0, stream>>>(Wb, Bt, Tb);
    k_oconv<<<dim3(64, 1, 4), 256, 0, stream>>>(owb, Tb, y2, stats);
    k_final<<<2048, 256, 0, stream>>>(y2, stats, gamma, beta, alpha, out);
}